// Round 3
// baseline (369.332 us; speedup 1.0000x reference)
//
#include <hip/hip_runtime.h>

// Layer_Hist: per-row 30-bin histogram of x[4096, 16384] fp32.
//   bin = floor(clamp(fma(x, invW, 15), 0, 29))
//   out column order: [bin0, bin29, bin1..bin28]
//
// R7: stream-continuity pass. R6 (occupancy 20->32 waves/CU) was neutral
// (-1.8 us) => kernel is NOT TLP/latency-limited; steady-state pipes say it
// should run ~43-45 us (VMEM 42.6, LDS-atomics ~10, VALU ~5 per CU), yet
// K is somewhere in (43,67). Residual = non-steady-state costs:
//   (a) per-row drain/refill: 1 row per block => at row end the load stream
//       drains (vmcnt(0)), epilogue+exit, next block pays a cold ~900-cyc
//       first-load with nothing in flight; 16 turnovers/CU, blocks mostly
//       in phase so they don't cover each other.
//   (b) nontemporal loads: nt bypasses L2 allocation; the 6.29 TB/s read
//       ceiling (m13) was measured with REGULAR float4 loads. Pure 256 MiB
//       stream has nothing to protect -- drop nt.
// Fix: persistent 2-row blocks (grid 2048 = exactly 8/CU resident, same
// occupancy), cross-row prefetch (row r+1 group 0 issued before row r's
// epilogue, so the VMEM stream never drains), h[] re-zeroed concurrently
// with the stage-2 store. Binning math byte-identical to R4/R6.
//
// Kept from R6: packed 2x u16 counters per LDS word (count<=64/field, no
// carry), COLS=128 -> within a wave all 64 lanes hit distinct words, 2-way
// bank aliasing (free per m136); LDS 16.3 KB; __launch_bounds__(256,8).

#define NBINS   30
#define THREADS 256
#define ROWLEN  16384
#define VPG     4                       // float4 per group per thread
#define GROUPS  (ROWLEN / 4 / THREADS / VPG)   // 4 groups per row
#define COLS    128                     // packed columns: 2 u16 fields/word
#define RPB     2                       // rows per block

typedef float f4 __attribute__((ext_vector_type(4)));

__global__ __launch_bounds__(THREADS, 8) void hist_kernel(
    const float* __restrict__ x, float* __restrict__ out)
{
    __shared__ unsigned int h[NBINS * COLS];     // 15360 B
    __shared__ unsigned int partial[8 * NBINS];  //   960 B

    const int t    = threadIdx.x;
    const int row0 = blockIdx.x * RPB;

    const float invW = 28.0f / 12.0f;   // 2.3333333f
    const float c15  = 15.0f;           // 6*invW + 1 (bin offset folded in)
    const unsigned int inc = 1u << ((t >> 7) << 4);  // t<128:+1 ; t>=128:+1<<16
    const int col = t & (COLS - 1);

#pragma unroll
    for (int i = 0; i < (NBINS * COLS) / THREADS; ++i)   // 15 words/thread
        h[i * THREADS + t] = 0u;
    __syncthreads();

    f4 cur[VPG], nxt[VPG];
    {
        const f4* xr0 = (const f4*)(x + (size_t)row0 * ROWLEN);
#pragma unroll
        for (int j = 0; j < VPG; ++j) cur[j] = xr0[t + j * THREADS];
    }

#pragma unroll 1
    for (int r = 0; r < RPB; ++r) {
        const f4* xr  = (const f4*)(x + (size_t)(row0 + r) * ROWLEN);
        const f4* xrn = (const f4*)(x + (size_t)(row0 + r + 1) * ROWLEN);

#pragma unroll 1
        for (int g = 0; g < GROUPS; ++g) {
            if (g + 1 < GROUPS) {                 // prefetch same row
#pragma unroll
                for (int j = 0; j < VPG; ++j)
                    nxt[j] = xr[t + ((g + 1) * VPG + j) * THREADS];
            } else if (r + 1 < RPB) {             // prefetch NEXT row grp 0
#pragma unroll
                for (int j = 0; j < VPG; ++j)
                    nxt[j] = xrn[t + j * THREADS];
            }
#pragma unroll
            for (int j = 0; j < VPG; ++j) {
                f4 v = cur[j];
#pragma unroll
                for (int c = 0; c < 4; ++c) {
                    float f = fmaf(v[c], invW, c15);
                    f = fminf(fmaxf(f, 0.0f), 29.0f);       // v_med3_f32
                    int bin = __float2int_rd(f);            // v_cvt_flr_i32
                    atomicAdd(&h[bin * COLS + col], inc);   // ds_add_u32
                }
            }
#pragma unroll
            for (int j = 0; j < VPG; ++j) cur[j] = nxt[j];
        }
        __syncthreads();   // main-loop ds_adds for row r complete

        // Stage 1: 240 threads = 30 bins x 8 groups of 16 words, rotated.
        if (t < 240) {
            const int b = t % NBINS;
            const int g = t / NBINS;
            unsigned int s = 0;
#pragma unroll
            for (int i = 0; i < 16; ++i) {
                unsigned int w = h[b * COLS + g * 16 + ((i + b) & 15)];
                s += (w & 0xFFFFu) + (w >> 16);
            }
            partial[g * NBINS + b] = s;
        }
        __syncthreads();   // h is dead from here; partial is ready

        // Stage 2 (t<30) runs concurrently with the h re-zero (all threads).
        if (t < NBINS) {
            unsigned int s = 0;
#pragma unroll
            for (int g = 0; g < 8; ++g) s += partial[g * NBINS + t];
            const int dst = (t == 0) ? 0 : (t == NBINS - 1) ? 1 : (t + 1);
            out[(size_t)(row0 + r) * NBINS + dst] = (float)s;
        }
        if (r + 1 < RPB) {
#pragma unroll
            for (int i = 0; i < (NBINS * COLS) / THREADS; ++i)
                h[i * THREADS + t] = 0u;
            __syncthreads();   // zeros visible before next row's ds_adds
        }
    }
}

extern "C" void kernel_launch(void* const* d_in, const int* in_sizes, int n_in,
                              void* d_out, int out_size, void* d_ws, size_t ws_size,
                              hipStream_t stream)
{
    const float* x  = (const float*)d_in[0];
    float* out      = (float*)d_out;
    const int rows  = in_sizes[0] / ROWLEN;   // 4096
    hist_kernel<<<rows / RPB, THREADS, 0, stream>>>(x, out);
}